// Round 1
// baseline (1011.893 us; speedup 1.0000x reference)
//
#include <hip/hip_runtime.h>

#define IN_F 256
#define OUT_F 128

// ---------------------------------------------------------------------------
// GEMM: z[n][o] = sum_k h[n][k] * W[o][k]   (h: [N,256] row-major, W: [128,256])
// 64x64 output tile per block, K-tiled by 64, 256 threads, 4x4 micro-tile.
// LDS tiles stored k-major (transposed) so the inner loop is two ds_read_b128
// (a-vector of 4 rows, b-vector of 4 cols) feeding 16 FMAs.
// ---------------------------------------------------------------------------
template <int BM, int BN, int BK>
__global__ __launch_bounds__(256) void gcn_gemm_kernel(
    const float* __restrict__ h, const float* __restrict__ W,
    float* __restrict__ z, int N)
{
    __shared__ float hsT[BK][BM + 4];  // stride 68: 4-way write conflict (ok), clean b128 reads
    __shared__ float wsT[BK][BN + 4];

    const int tid  = threadIdx.x;
    const int row0 = blockIdx.x * BM;
    const int col0 = blockIdx.y * BN;
    const int rt   = tid >> 4;   // 0..15 (row group)
    const int ct   = tid & 15;   // 0..15 (col group)

    // staging assignment: each thread loads 16 floats of h-tile and 16 of W-tile
    const int lr = tid >> 2;          // 0..63: tile row
    const int lk = (tid & 3) * 16;    // k-offset group

    float acc[4][4] = {};

    for (int kt = 0; kt < IN_F; kt += BK) {
        // stage h[row0 .. row0+63][kt .. kt+63] -> hsT[k][r]
        #pragma unroll
        for (int j = 0; j < 4; ++j) {
            const int k = lk + 4 * j;
            float4 v = make_float4(0.f, 0.f, 0.f, 0.f);
            const int grow = row0 + lr;
            if (grow < N)
                v = *(const float4*)&h[(size_t)grow * IN_F + kt + k];
            hsT[k + 0][lr] = v.x; hsT[k + 1][lr] = v.y;
            hsT[k + 2][lr] = v.z; hsT[k + 3][lr] = v.w;
        }
        // stage W[col0 .. col0+63][kt .. kt+63] -> wsT[k][c]  (always in range)
        #pragma unroll
        for (int j = 0; j < 4; ++j) {
            const int k = lk + 4 * j;
            const float4 v = *(const float4*)&W[(size_t)(col0 + lr) * IN_F + kt + k];
            wsT[k + 0][lr] = v.x; wsT[k + 1][lr] = v.y;
            wsT[k + 2][lr] = v.z; wsT[k + 3][lr] = v.w;
        }
        __syncthreads();

        #pragma unroll 8
        for (int k = 0; k < BK; ++k) {
            const float4 av = *(const float4*)&hsT[k][rt * 4];
            const float4 bv = *(const float4*)&wsT[k][ct * 4];
            const float a_[4] = {av.x, av.y, av.z, av.w};
            const float b_[4] = {bv.x, bv.y, bv.z, bv.w};
            #pragma unroll
            for (int i = 0; i < 4; ++i)
                #pragma unroll
                for (int j = 0; j < 4; ++j)
                    acc[i][j] = fmaf(a_[i], b_[j], acc[i][j]);
        }
        __syncthreads();
    }

    #pragma unroll
    for (int i = 0; i < 4; ++i) {
        const int grow = row0 + rt * 4 + i;
        if (grow < N) {
            const float4 o = make_float4(acc[i][0], acc[i][1], acc[i][2], acc[i][3]);
            *(float4*)&z[(size_t)grow * OUT_F + col0 + ct * 4] = o;
        }
    }
}

// ---------------------------------------------------------------------------
// Edge-parallel scatter: 128 threads per edge (2 edges per 256-thread block).
// agg[dst] += z[src] via f32 atomics; lane 0 counts degree.
// ---------------------------------------------------------------------------
__global__ __launch_bounds__(256) void gcn_scatter_kernel(
    const float* __restrict__ z, const int* __restrict__ src,
    const int* __restrict__ dst, float* __restrict__ agg,
    float* __restrict__ deg, int E)
{
    const int e = blockIdx.x * 2 + (threadIdx.x >> 7);
    if (e >= E) return;
    const int t = threadIdx.x & 127;
    const int s = src[e];
    const int d = dst[e];
    atomicAdd(&agg[(size_t)d * OUT_F + t], z[(size_t)s * OUT_F + t]);
    if (t == 0) atomicAdd(&deg[d], 1.0f);
}

// ---------------------------------------------------------------------------
// out[n][f] = agg[n][f] / max(deg[n], 1)    (in-place on d_out, float4)
// ---------------------------------------------------------------------------
__global__ __launch_bounds__(256) void gcn_finalize_kernel(
    float* __restrict__ out, const float* __restrict__ deg, int n4)
{
    const int i = blockIdx.x * 256 + threadIdx.x;
    if (i >= n4) return;
    float4 v = ((const float4*)out)[i];
    const float dg = fmaxf(deg[i >> 5], 1.0f);  // elem idx = i*4, node = (i*4)>>7
    const float r = 1.0f / dg;
    v.x *= r; v.y *= r; v.z *= r; v.w *= r;
    ((float4*)out)[i] = v;
}

extern "C" void kernel_launch(void* const* d_in, const int* in_sizes, int n_in,
                              void* d_out, int out_size, void* d_ws, size_t ws_size,
                              hipStream_t stream)
{
    const float* h   = (const float*)d_in[0];
    const float* W   = (const float*)d_in[1];
    const int*   src = (const int*)d_in[2];
    const int*   dst = (const int*)d_in[3];
    float*       out = (float*)d_out;

    const int N = in_sizes[0] / IN_F;   // 100000
    const int E = in_sizes[2];          // 1600000

    float* z   = (float*)d_ws;                    // [N, OUT_F]
    float* deg = z + (size_t)N * OUT_F;           // [N]

    hipMemsetAsync(d_out, 0, (size_t)out_size * sizeof(float), stream);
    hipMemsetAsync(deg, 0, (size_t)N * sizeof(float), stream);

    dim3 ggrid((N + 63) / 64, OUT_F / 64);
    gcn_gemm_kernel<64, 64, 64><<<ggrid, 256, 0, stream>>>(h, W, z, N);

    gcn_scatter_kernel<<<(E + 1) / 2, 256, 0, stream>>>(z, src, dst, out, deg, E);

    const int n4 = out_size / 4;
    gcn_finalize_kernel<<<(n4 + 255) / 256, 256, 0, stream>>>(out, deg, n4);
}

// Round 2
// 566.065 us; speedup vs baseline: 1.7876x; 1.7876x over previous
//
#include <hip/hip_runtime.h>

#define IN_F 256
#define OUT_F 128

// ---------------------------------------------------------------------------
// GEMM: z[n][o] = sum_k h[n][k] * W[o][k]   (unchanged this round)
// ---------------------------------------------------------------------------
template <int BM, int BN, int BK>
__global__ __launch_bounds__(256) void gcn_gemm_kernel(
    const float* __restrict__ h, const float* __restrict__ W,
    float* __restrict__ z, int N)
{
    __shared__ float hsT[BK][BM + 4];
    __shared__ float wsT[BK][BN + 4];

    const int tid  = threadIdx.x;
    const int row0 = blockIdx.x * BM;
    const int col0 = blockIdx.y * BN;
    const int rt   = tid >> 4;
    const int ct   = tid & 15;

    const int lr = tid >> 2;
    const int lk = (tid & 3) * 16;

    float acc[4][4] = {};

    for (int kt = 0; kt < IN_F; kt += BK) {
        #pragma unroll
        for (int j = 0; j < 4; ++j) {
            const int k = lk + 4 * j;
            float4 v = make_float4(0.f, 0.f, 0.f, 0.f);
            const int grow = row0 + lr;
            if (grow < N)
                v = *(const float4*)&h[(size_t)grow * IN_F + kt + k];
            hsT[k + 0][lr] = v.x; hsT[k + 1][lr] = v.y;
            hsT[k + 2][lr] = v.z; hsT[k + 3][lr] = v.w;
        }
        #pragma unroll
        for (int j = 0; j < 4; ++j) {
            const int k = lk + 4 * j;
            const float4 v = *(const float4*)&W[(size_t)(col0 + lr) * IN_F + kt + k];
            wsT[k + 0][lr] = v.x; wsT[k + 1][lr] = v.y;
            wsT[k + 2][lr] = v.z; wsT[k + 3][lr] = v.w;
        }
        __syncthreads();

        #pragma unroll 8
        for (int k = 0; k < BK; ++k) {
            const float4 av = *(const float4*)&hsT[k][rt * 4];
            const float4 bv = *(const float4*)&wsT[k][ct * 4];
            const float a_[4] = {av.x, av.y, av.z, av.w};
            const float b_[4] = {bv.x, bv.y, bv.z, bv.w};
            #pragma unroll
            for (int i = 0; i < 4; ++i)
                #pragma unroll
                for (int j = 0; j < 4; ++j)
                    acc[i][j] = fmaf(a_[i], b_[j], acc[i][j]);
        }
        __syncthreads();
    }

    #pragma unroll
    for (int i = 0; i < 4; ++i) {
        const int grow = row0 + rt * 4 + i;
        if (grow < N) {
            const float4 o = make_float4(acc[i][0], acc[i][1], acc[i][2], acc[i][3]);
            *(float4*)&z[(size_t)grow * OUT_F + col0 + ct * 4] = o;
        }
    }
}

// ---------------------------------------------------------------------------
// CSR build: histogram -> 3-step exclusive scan -> bucket fill
// ---------------------------------------------------------------------------
__global__ __launch_bounds__(256) void gcn_hist_kernel(
    const int* __restrict__ dst, int* __restrict__ cnt, int E)
{
    int i = blockIdx.x * 256 + threadIdx.x;
    const int stride = gridDim.x * 256;
    for (; i < E; i += stride)
        atomicAdd(&cnt[dst[i]], 1);
}

template <int BS>
__global__ __launch_bounds__(BS) void gcn_scan_bsum_kernel(
    const int* __restrict__ cnt, int* __restrict__ bsum, int N)
{
    __shared__ int sm[BS];
    const int i = blockIdx.x * BS + threadIdx.x;
    sm[threadIdx.x] = (i < N) ? cnt[i] : 0;
    __syncthreads();
    #pragma unroll
    for (int s = BS / 2; s > 0; s >>= 1) {
        if (threadIdx.x < s) sm[threadIdx.x] += sm[threadIdx.x + s];
        __syncthreads();
    }
    if (threadIdx.x == 0) bsum[blockIdx.x] = sm[0];
}

__global__ void gcn_scan_top_kernel(int* __restrict__ bsum, int nb)
{
    // single thread: nb ~ 196, trivial
    int acc = 0;
    for (int i = 0; i < nb; ++i) { const int v = bsum[i]; bsum[i] = acc; acc += v; }
}

template <int BS>
__global__ __launch_bounds__(BS) void gcn_scan_final_kernel(
    const int* __restrict__ cnt, const int* __restrict__ bsum,
    int* __restrict__ off, int* __restrict__ cur, int N)
{
    __shared__ int sm[BS];
    const int i = blockIdx.x * BS + threadIdx.x;
    const int v = (i < N) ? cnt[i] : 0;
    sm[threadIdx.x] = v;
    __syncthreads();
    #pragma unroll
    for (int s = 1; s < BS; s <<= 1) {
        const int t = (threadIdx.x >= s) ? sm[threadIdx.x - s] : 0;
        __syncthreads();
        sm[threadIdx.x] += t;
        __syncthreads();
    }
    if (i < N) {
        const int excl = sm[threadIdx.x] - v + bsum[blockIdx.x];
        off[i] = excl;
        cur[i] = excl;
    }
}

__global__ __launch_bounds__(256) void gcn_fill_kernel(
    const int* __restrict__ src, const int* __restrict__ dst,
    int* __restrict__ cur, int* __restrict__ csr, int E)
{
    int i = blockIdx.x * 256 + threadIdx.x;
    const int stride = gridDim.x * 256;
    for (; i < E; i += stride) {
        const int d = dst[i];
        const int pos = atomicAdd(&cur[d], 1);
        csr[pos] = src[i];
    }
}

// ---------------------------------------------------------------------------
// Gather-aggregate + fused mean: one wave per node, lane = float2 column pair.
// Per edge the wave reads one contiguous 512 B row of z (coalesced).
// ---------------------------------------------------------------------------
__global__ __launch_bounds__(256) void gcn_gather_kernel(
    const float* __restrict__ z, const int* __restrict__ csr,
    const int* __restrict__ off, const int* __restrict__ cnt,
    float* __restrict__ out, int N)
{
    const int wave = threadIdx.x >> 6;
    const int lane = threadIdx.x & 63;
    const int n = blockIdx.x * 4 + wave;
    if (n >= N) return;

    const int beg = off[n];
    const int c   = cnt[n];

    float2 acc = make_float2(0.f, 0.f);
    int e = 0;
    for (; e + 4 <= c; e += 4) {
        const int s0 = csr[beg + e + 0];
        const int s1 = csr[beg + e + 1];
        const int s2 = csr[beg + e + 2];
        const int s3 = csr[beg + e + 3];
        const float2 v0 = ((const float2*)(z + (size_t)s0 * OUT_F))[lane];
        const float2 v1 = ((const float2*)(z + (size_t)s1 * OUT_F))[lane];
        const float2 v2 = ((const float2*)(z + (size_t)s2 * OUT_F))[lane];
        const float2 v3 = ((const float2*)(z + (size_t)s3 * OUT_F))[lane];
        acc.x += v0.x + v1.x + v2.x + v3.x;
        acc.y += v0.y + v1.y + v2.y + v3.y;
    }
    for (; e < c; ++e) {
        const int s = csr[beg + e];
        const float2 v = ((const float2*)(z + (size_t)s * OUT_F))[lane];
        acc.x += v.x; acc.y += v.y;
    }

    const float r = 1.0f / fmaxf((float)c, 1.0f);
    const float2 o = make_float2(acc.x * r, acc.y * r);
    ((float2*)(out + (size_t)n * OUT_F))[lane] = o;
}

extern "C" void kernel_launch(void* const* d_in, const int* in_sizes, int n_in,
                              void* d_out, int out_size, void* d_ws, size_t ws_size,
                              hipStream_t stream)
{
    const float* h   = (const float*)d_in[0];
    const float* W   = (const float*)d_in[1];
    const int*   src = (const int*)d_in[2];
    const int*   dst = (const int*)d_in[3];
    float*       out = (float*)d_out;

    const int N = in_sizes[0] / IN_F;   // 100000
    const int E = in_sizes[2];          // 1600000

    constexpr int SBS = 512;            // scan block size
    const int NB = (N + SBS - 1) / SBS; // scan blocks (196)

    float* z    = (float*)d_ws;                    // [N, OUT_F] 51.2 MB
    int*   cnt  = (int*)(z + (size_t)N * OUT_F);   // [N]
    int*   off  = cnt + N;                         // [N]
    int*   cur  = off + N;                         // [N]
    int*   csr  = cur + N;                         // [E]
    int*   bsum = csr + E;                         // [NB]

    hipMemsetAsync(cnt, 0, (size_t)N * sizeof(int), stream);

    dim3 ggrid((N + 63) / 64, OUT_F / 64);
    gcn_gemm_kernel<64, 64, 64><<<ggrid, 256, 0, stream>>>(h, W, z, N);

    gcn_hist_kernel<<<2048, 256, 0, stream>>>(dst, cnt, E);
    gcn_scan_bsum_kernel<SBS><<<NB, SBS, 0, stream>>>(cnt, bsum, N);
    gcn_scan_top_kernel<<<1, 1, 0, stream>>>(bsum, NB);
    gcn_scan_final_kernel<SBS><<<NB, SBS, 0, stream>>>(cnt, bsum, off, cur, N);
    gcn_fill_kernel<<<2048, 256, 0, stream>>>(src, dst, cur, csr, E);

    gcn_gather_kernel<<<(N + 3) / 4, 256, 0, stream>>>(z, csr, off, cnt, out, N);
}

// Round 3
// 473.648 us; speedup vs baseline: 2.1364x; 1.1951x over previous
//
#include <hip/hip_runtime.h>

#define IN_F 256
#define OUT_F 128

typedef __attribute__((ext_vector_type(8))) short short8;
typedef __attribute__((ext_vector_type(4))) float floatx4;

__device__ __forceinline__ ushort f2b(float x) {
    union { float f; uint u; } v; v.f = x;
    const uint r = v.u + 0x7FFFu + ((v.u >> 16) & 1u);  // RNE
    return (ushort)(r >> 16);
}
__device__ __forceinline__ float blo(uint u) {
    union { uint u; float f; } v; v.u = u << 16; return v.f;
}
__device__ __forceinline__ float bhi(uint u) {
    union { uint u; float f; } v; v.u = u & 0xFFFF0000u; return v.f;
}

// ---------------------------------------------------------------------------
// bf16-MFMA GEMM: z[n][o] = sum_k h[n][k] * W[o][k], z stored bf16.
// 256 thr / 4 waves; block M-tile 256 (64 rows/wave); full W in LDS as bf16
// with granule^=(o&7) XOR swizzle so B-frag ds_read_b128 is conflict-free.
// A-frags load direct from global (h has no cross-wave reuse), reg double-buf.
// ---------------------------------------------------------------------------
__global__ __launch_bounds__(256) void gcn_gemm_mfma_kernel(
    const float* __restrict__ h, const float* __restrict__ W,
    ushort* __restrict__ zb, int N)
{
    __shared__ ushort Wl[OUT_F * IN_F];  // 64 KB bf16

    const int tid = threadIdx.x;

    // stage W -> LDS (convert fp32->bf16, swizzled granules of 8 elems/16B)
    for (int G = tid; G < OUT_F * IN_F / 8; G += 256) {
        const int o = G >> 5, g = G & 31;
        const float4 v0 = *(const float4*)&W[o * IN_F + g * 8];
        const float4 v1 = *(const float4*)&W[o * IN_F + g * 8 + 4];
        short8 s;
        s[0] = (short)f2b(v0.x); s[1] = (short)f2b(v0.y);
        s[2] = (short)f2b(v0.z); s[3] = (short)f2b(v0.w);
        s[4] = (short)f2b(v1.x); s[5] = (short)f2b(v1.y);
        s[6] = (short)f2b(v1.z); s[7] = (short)f2b(v1.w);
        *(short8*)&Wl[o * IN_F + ((g ^ (o & 7)) << 3)] = s;
    }
    __syncthreads();

    const int wid = tid >> 6, lane = tid & 63;
    const int l15 = lane & 15, hi = lane >> 4;
    const int row0 = blockIdx.x * 256 + wid * 64;

    floatx4 acc[4][8];
    #pragma unroll
    for (int m = 0; m < 4; ++m)
        #pragma unroll
        for (int f = 0; f < 8; ++f)
            acc[m][f] = (floatx4){0.f, 0.f, 0.f, 0.f};

    int rowm[4];
    #pragma unroll
    for (int m = 0; m < 4; ++m) {
        const int r = row0 + m * 16 + l15;
        rowm[m] = (r < N) ? r : (N - 1);  // clamp; garbage rows never stored
    }

    float4 buf[2][4][2];  // reg double-buffer for A (static parity idx via unroll)
    #pragma unroll
    for (int m = 0; m < 4; ++m) {
        const float* hp = h + (size_t)rowm[m] * IN_F + hi * 8;
        buf[0][m][0] = *(const float4*)hp;
        buf[0][m][1] = *(const float4*)(hp + 4);
    }

    #pragma unroll
    for (int ks = 0; ks < 8; ++ks) {
        const int cur = ks & 1, nxt = cur ^ 1;
        if (ks < 7) {
            #pragma unroll
            for (int m = 0; m < 4; ++m) {
                const float* hp = h + (size_t)rowm[m] * IN_F + (ks + 1) * 32 + hi * 8;
                buf[nxt][m][0] = *(const float4*)hp;
                buf[nxt][m][1] = *(const float4*)(hp + 4);
            }
        }
        short8 af[4];
        #pragma unroll
        for (int m = 0; m < 4; ++m) {
            const float4 a0 = buf[cur][m][0], a1 = buf[cur][m][1];
            short8 s;
            s[0] = (short)f2b(a0.x); s[1] = (short)f2b(a0.y);
            s[2] = (short)f2b(a0.z); s[3] = (short)f2b(a0.w);
            s[4] = (short)f2b(a1.x); s[5] = (short)f2b(a1.y);
            s[6] = (short)f2b(a1.z); s[7] = (short)f2b(a1.w);
            af[m] = s;
        }
        // B-frag: o = f*16+l15, k-granule = ks*4+hi, swizzle ^ (o&7)==(l15&7)
        const int gsw = ((ks * 4 + hi) ^ (l15 & 7)) << 3;
        #pragma unroll
        for (int f = 0; f < 8; ++f) {
            const short8 bfr = *(const short8*)&Wl[(f * 16 + l15) * IN_F + gsw];
            #pragma unroll
            for (int m = 0; m < 4; ++m)
                acc[m][f] = __builtin_amdgcn_mfma_f32_16x16x32_bf16(
                    af[m], bfr, acc[m][f], 0, 0, 0);
        }
    }

    // C/D layout: col = lane&15, row = (lane>>4)*4 + reg  [m89 verified]
    #pragma unroll
    for (int m = 0; m < 4; ++m) {
        #pragma unroll
        for (int r = 0; r < 4; ++r) {
            const int row = row0 + m * 16 + hi * 4 + r;
            if (row < N) {
                ushort* zp = zb + (size_t)row * OUT_F + l15;
                #pragma unroll
                for (int f = 0; f < 8; ++f)
                    zp[f * 16] = f2b(acc[m][f][r]);
            }
        }
    }
}

// ---------------------------------------------------------------------------
// CSR build: histogram -> 3-step exclusive scan -> bucket fill (unchanged)
// ---------------------------------------------------------------------------
__global__ __launch_bounds__(256) void gcn_hist_kernel(
    const int* __restrict__ dst, int* __restrict__ cnt, int E)
{
    int i = blockIdx.x * 256 + threadIdx.x;
    const int stride = gridDim.x * 256;
    for (; i < E; i += stride)
        atomicAdd(&cnt[dst[i]], 1);
}

template <int BS>
__global__ __launch_bounds__(BS) void gcn_scan_bsum_kernel(
    const int* __restrict__ cnt, int* __restrict__ bsum, int N)
{
    __shared__ int sm[BS];
    const int i = blockIdx.x * BS + threadIdx.x;
    sm[threadIdx.x] = (i < N) ? cnt[i] : 0;
    __syncthreads();
    #pragma unroll
    for (int s = BS / 2; s > 0; s >>= 1) {
        if (threadIdx.x < s) sm[threadIdx.x] += sm[threadIdx.x + s];
        __syncthreads();
    }
    if (threadIdx.x == 0) bsum[blockIdx.x] = sm[0];
}

__global__ void gcn_scan_top_kernel(int* __restrict__ bsum, int nb)
{
    int acc = 0;
    for (int i = 0; i < nb; ++i) { const int v = bsum[i]; bsum[i] = acc; acc += v; }
}

template <int BS>
__global__ __launch_bounds__(BS) void gcn_scan_final_kernel(
    const int* __restrict__ cnt, const int* __restrict__ bsum,
    int* __restrict__ off, int* __restrict__ cur, int N)
{
    __shared__ int sm[BS];
    const int i = blockIdx.x * BS + threadIdx.x;
    const int v = (i < N) ? cnt[i] : 0;
    sm[threadIdx.x] = v;
    __syncthreads();
    #pragma unroll
    for (int s = 1; s < BS; s <<= 1) {
        const int t = (threadIdx.x >= s) ? sm[threadIdx.x - s] : 0;
        __syncthreads();
        sm[threadIdx.x] += t;
        __syncthreads();
    }
    if (i < N) {
        const int excl = sm[threadIdx.x] - v + bsum[blockIdx.x];
        off[i] = excl;
        cur[i] = excl;
    }
}

__global__ __launch_bounds__(256) void gcn_fill_kernel(
    const int* __restrict__ src, const int* __restrict__ dst,
    int* __restrict__ cur, int* __restrict__ csr, int E)
{
    int i = blockIdx.x * 256 + threadIdx.x;
    const int stride = gridDim.x * 256;
    for (; i < E; i += stride) {
        const int d = dst[i];
        const int pos = atomicAdd(&cur[d], 1);
        csr[pos] = src[i];
    }
}

// ---------------------------------------------------------------------------
// Gather-aggregate + fused mean: one wave/node, lane = uint (2 bf16 cols).
// z row = 256 B coalesced per edge; accumulate fp32; out fp32.
// ---------------------------------------------------------------------------
__global__ __launch_bounds__(256) void gcn_gather_kernel(
    const uint* __restrict__ z2, const int* __restrict__ csr,
    const int* __restrict__ off, const int* __restrict__ cnt,
    float* __restrict__ out, int N)
{
    const int wave = threadIdx.x >> 6;
    const int lane = threadIdx.x & 63;
    const int n = blockIdx.x * 4 + wave;
    if (n >= N) return;

    const int beg = off[n];
    const int c   = cnt[n];

    float ax = 0.f, ay = 0.f;
    int e = 0;
    for (; e + 4 <= c; e += 4) {
        const int s0 = csr[beg + e + 0];
        const int s1 = csr[beg + e + 1];
        const int s2 = csr[beg + e + 2];
        const int s3 = csr[beg + e + 3];
        const uint u0 = z2[(size_t)s0 * (OUT_F / 2) + lane];
        const uint u1 = z2[(size_t)s1 * (OUT_F / 2) + lane];
        const uint u2 = z2[(size_t)s2 * (OUT_F / 2) + lane];
        const uint u3 = z2[(size_t)s3 * (OUT_F / 2) + lane];
        ax += blo(u0) + blo(u1) + blo(u2) + blo(u3);
        ay += bhi(u0) + bhi(u1) + bhi(u2) + bhi(u3);
    }
    for (; e < c; ++e) {
        const int s = csr[beg + e];
        const uint u = z2[(size_t)s * (OUT_F / 2) + lane];
        ax += blo(u); ay += bhi(u);
    }

    const float r = 1.0f / fmaxf((float)c, 1.0f);
    ((float2*)(out + (size_t)n * OUT_F))[lane] = make_float2(ax * r, ay * r);
}

extern "C" void kernel_launch(void* const* d_in, const int* in_sizes, int n_in,
                              void* d_out, int out_size, void* d_ws, size_t ws_size,
                              hipStream_t stream)
{
    const float* h   = (const float*)d_in[0];
    const float* W   = (const float*)d_in[1];
    const int*   src = (const int*)d_in[2];
    const int*   dst = (const int*)d_in[3];
    float*       out = (float*)d_out;

    const int N = in_sizes[0] / IN_F;   // 100000
    const int E = in_sizes[2];          // 1600000

    constexpr int SBS = 512;
    const int NB = (N + SBS - 1) / SBS;

    ushort* zb  = (ushort*)d_ws;                        // [N, OUT_F] bf16, 25.6 MB
    int*    cnt = (int*)(zb + (size_t)N * OUT_F);       // [N]
    int*    off = cnt + N;                              // [N]
    int*    cur = off + N;                              // [N]
    int*    csr = cur + N;                              // [E]
    int*    bsum = csr + E;                             // [NB]

    hipMemsetAsync(cnt, 0, (size_t)N * sizeof(int), stream);

    gcn_gemm_mfma_kernel<<<(N + 255) / 256, 256, 0, stream>>>(h, W, zb, N);

    gcn_hist_kernel<<<2048, 256, 0, stream>>>(dst, cnt, E);
    gcn_scan_bsum_kernel<SBS><<<NB, SBS, 0, stream>>>(cnt, bsum, N);
    gcn_scan_top_kernel<<<1, 1, 0, stream>>>(bsum, NB);
    gcn_scan_final_kernel<SBS><<<NB, SBS, 0, stream>>>(cnt, bsum, off, cur, N);
    gcn_fill_kernel<<<2048, 256, 0, stream>>>(src, dst, cur, csr, E);

    gcn_gather_kernel<<<(N + 3) / 4, 256, 0, stream>>>((const uint*)zb, csr, off, cnt, out, N);
}

// Round 5
// 311.688 us; speedup vs baseline: 3.2465x; 1.5196x over previous
//
#include <hip/hip_runtime.h>

#define IN_F 256
#define OUT_F 128
#define NPB 128          // nodes per bucket (dst >> 7)
#define MAXB 1024        // max buckets supported (N <= 131072)
#define CAP 4096         // per-bucket edge capacity in LDS (mean 2046, sigma 45)

typedef __attribute__((ext_vector_type(8))) short short8;
typedef __attribute__((ext_vector_type(4))) float floatx4;

__device__ __forceinline__ ushort f2b(float x) {
    union { float f; uint u; } v; v.f = x;
    const uint r = v.u + 0x7FFFu + ((v.u >> 16) & 1u);  // RNE
    return (ushort)(r >> 16);
}
__device__ __forceinline__ float blo(uint u) {
    union { uint u; float f; } v; v.u = u << 16; return v.f;
}
__device__ __forceinline__ float bhi(uint u) {
    union { uint u; float f; } v; v.u = u & 0xFFFF0000u; return v.f;
}

// ---------------------------------------------------------------------------
// bf16-MFMA GEMM: z[n][o] = sum_k h[n][k] * W[o][k], z stored bf16. Unchanged.
// ---------------------------------------------------------------------------
__global__ __launch_bounds__(256) void gcn_gemm_mfma_kernel(
    const float* __restrict__ h, const float* __restrict__ W,
    ushort* __restrict__ zb, int N)
{
    __shared__ ushort Wl[OUT_F * IN_F];  // 64 KB bf16

    const int tid = threadIdx.x;

    for (int G = tid; G < OUT_F * IN_F / 8; G += 256) {
        const int o = G >> 5, g = G & 31;
        const float4 v0 = *(const float4*)&W[o * IN_F + g * 8];
        const float4 v1 = *(const float4*)&W[o * IN_F + g * 8 + 4];
        short8 s;
        s[0] = (short)f2b(v0.x); s[1] = (short)f2b(v0.y);
        s[2] = (short)f2b(v0.z); s[3] = (short)f2b(v0.w);
        s[4] = (short)f2b(v1.x); s[5] = (short)f2b(v1.y);
        s[6] = (short)f2b(v1.z); s[7] = (short)f2b(v1.w);
        *(short8*)&Wl[o * IN_F + ((g ^ (o & 7)) << 3)] = s;
    }
    __syncthreads();

    const int wid = tid >> 6, lane = tid & 63;
    const int l15 = lane & 15, hi = lane >> 4;
    const int row0 = blockIdx.x * 256 + wid * 64;

    floatx4 acc[4][8];
    #pragma unroll
    for (int m = 0; m < 4; ++m)
        #pragma unroll
        for (int f = 0; f < 8; ++f)
            acc[m][f] = (floatx4){0.f, 0.f, 0.f, 0.f};

    int rowm[4];
    #pragma unroll
    for (int m = 0; m < 4; ++m) {
        const int r = row0 + m * 16 + l15;
        rowm[m] = (r < N) ? r : (N - 1);
    }

    float4 buf[2][4][2];
    #pragma unroll
    for (int m = 0; m < 4; ++m) {
        const float* hp = h + (size_t)rowm[m] * IN_F + hi * 8;
        buf[0][m][0] = *(const float4*)hp;
        buf[0][m][1] = *(const float4*)(hp + 4);
    }

    #pragma unroll
    for (int ks = 0; ks < 8; ++ks) {
        const int cur = ks & 1, nxt = cur ^ 1;
        if (ks < 7) {
            #pragma unroll
            for (int m = 0; m < 4; ++m) {
                const float* hp = h + (size_t)rowm[m] * IN_F + (ks + 1) * 32 + hi * 8;
                buf[nxt][m][0] = *(const float4*)hp;
                buf[nxt][m][1] = *(const float4*)(hp + 4);
            }
        }
        short8 af[4];
        #pragma unroll
        for (int m = 0; m < 4; ++m) {
            const float4 a0 = buf[cur][m][0], a1 = buf[cur][m][1];
            short8 s;
            s[0] = (short)f2b(a0.x); s[1] = (short)f2b(a0.y);
            s[2] = (short)f2b(a0.z); s[3] = (short)f2b(a0.w);
            s[4] = (short)f2b(a1.x); s[5] = (short)f2b(a1.y);
            s[6] = (short)f2b(a1.z); s[7] = (short)f2b(a1.w);
            af[m] = s;
        }
        const int gsw = ((ks * 4 + hi) ^ (l15 & 7)) << 3;
        #pragma unroll
        for (int f = 0; f < 8; ++f) {
            const short8 bfr = *(const short8*)&Wl[(f * 16 + l15) * IN_F + gsw];
            #pragma unroll
            for (int m = 0; m < 4; ++m)
                acc[m][f] = __builtin_amdgcn_mfma_f32_16x16x32_bf16(
                    af[m], bfr, acc[m][f], 0, 0, 0);
        }
    }

    #pragma unroll
    for (int m = 0; m < 4; ++m) {
        #pragma unroll
        for (int r = 0; r < 4; ++r) {
            const int row = row0 + m * 16 + hi * 4 + r;
            if (row < N) {
                ushort* zp = zb + (size_t)row * OUT_F + l15;
                #pragma unroll
                for (int f = 0; f < 8; ++f)
                    zp[f * 16] = f2b(acc[m][f][r]);
            }
        }
    }
}

// ---------------------------------------------------------------------------
// Coarse bucket histogram: LDS-binned, one global atomic per (block, bucket).
// ---------------------------------------------------------------------------
__global__ __launch_bounds__(256) void gcn_bhist_kernel(
    const int* __restrict__ dst, int* __restrict__ gcnt,
    int E, int nb, int chunk)
{
    __shared__ int hist[MAXB];
    for (int b = threadIdx.x; b < nb; b += 256) hist[b] = 0;
    __syncthreads();
    const int e0 = blockIdx.x * chunk;
    const int e1 = min(E, e0 + chunk);
    for (int i = e0 + threadIdx.x; i < e1; i += 256)
        atomicAdd(&hist[dst[i] >> 7], 1);
    __syncthreads();
    for (int b = threadIdx.x; b < nb; b += 256)
        if (hist[b]) atomicAdd(&gcnt[b], hist[b]);
}

// ---------------------------------------------------------------------------
// Bucket-offset scan (nb <= 1024): one block, Hillis-Steele in LDS.
// ---------------------------------------------------------------------------
__global__ __launch_bounds__(1024) void gcn_bscan_kernel(
    const int* __restrict__ gcnt, int* __restrict__ off,
    int* __restrict__ cur, int nb)
{
    __shared__ int sm[1024];
    const int t = threadIdx.x;
    const int v = (t < nb) ? gcnt[t] : 0;
    sm[t] = v;
    __syncthreads();
    #pragma unroll
    for (int s = 1; s < 1024; s <<= 1) {
        const int u = (t >= s) ? sm[t - s] : 0;
        __syncthreads();
        sm[t] += u;
        __syncthreads();
    }
    if (t < nb) { const int excl = sm[t] - v; off[t] = excl; cur[t] = excl; }
}

// ---------------------------------------------------------------------------
// Partition: place packed (dstLow<<17 | src) into bucket segments.
// Ranks via LDS cursors (fast); one global atomic per (block,bucket) reserves
// a contiguous run -> writes are ~8-entry runs, not fully random 4B stores.
// ---------------------------------------------------------------------------
__global__ __launch_bounds__(256) void gcn_part_kernel(
    const int* __restrict__ src, const int* __restrict__ dst,
    int* __restrict__ cur, uint* __restrict__ csr,
    int E, int nb, int chunk)
{
    __shared__ int hist[MAXB];
    __shared__ int base[MAXB];
    const int tid = threadIdx.x;
    const int e0 = blockIdx.x * chunk;
    const int e1 = min(E, e0 + chunk);

    for (int b = tid; b < nb; b += 256) hist[b] = 0;
    __syncthreads();
    for (int i = e0 + tid; i < e1; i += 256)
        atomicAdd(&hist[dst[i] >> 7], 1);
    __syncthreads();
    for (int b = tid; b < nb; b += 256) {
        const int hc = hist[b];
        base[b] = hc ? atomicAdd(&cur[b], hc) : 0;
        hist[b] = 0;
    }
    __syncthreads();
    for (int i = e0 + tid; i < e1; i += 256) {
        const int d = dst[i];
        const int bk = d >> 7;
        const int r = atomicAdd(&hist[bk], 1);
        csr[base[bk] + r] = (uint)src[i] | ((uint)(d & 127) << 17);
    }
}

// ---------------------------------------------------------------------------
// Fused fine-sort + pull-gather + mean. One block per bucket (128 nodes).
// Sort bucket edges by node in LDS (count -> scan -> place), then wave/node
// register-accumulated gather of z rows, divide by count, store.
// ---------------------------------------------------------------------------
__global__ __launch_bounds__(512) void gcn_sortgather_kernel(
    const uint* __restrict__ z2, const uint* __restrict__ csr,
    const int* __restrict__ off, const int* __restrict__ gcnt,
    float* __restrict__ out, int N)
{
    __shared__ uint eLDS[CAP];
    __shared__ int fcnt[NPB];
    __shared__ int fcur[NPB];
    __shared__ int foff[NPB + 1];

    const int bk   = blockIdx.x;
    const int tid  = threadIdx.x;
    const int beg  = off[bk];
    const int cnt  = gcnt[bk];
    const int n0   = bk * NPB;
    const int wave = tid >> 6, lane = tid & 63;

    if (tid < NPB) { fcnt[tid] = 0; fcur[tid] = 0; }
    __syncthreads();

    if (cnt <= CAP) {
        // pass 1: count per node
        for (int i = tid; i < cnt; i += 512)
            atomicAdd(&fcnt[csr[beg + i] >> 17], 1);
        __syncthreads();
        if (tid == 0) {
            int a = 0;
            #pragma unroll 4
            for (int j = 0; j < NPB; ++j) { foff[j] = a; a += fcnt[j]; }
            foff[NPB] = a;
        }
        __syncthreads();
        // pass 2: place node-sorted into LDS
        for (int i = tid; i < cnt; i += 512) {
            const uint p = csr[beg + i];
            const int  j = (int)(p >> 17);
            const int  r = atomicAdd(&fcur[j], 1);
            eLDS[foff[j] + r] = p;
        }
        __syncthreads();
        // pull-gather: wave w -> nodes w, w+8, ...
        for (int j = wave; j < NPB; j += 8) {
            const int n = n0 + j;
            if (n >= N) continue;
            const int s0 = foff[j], s1 = foff[j + 1];
            float ax = 0.f, ay = 0.f;
            int e = s0;
            for (; e + 4 <= s1; e += 4) {
                const uint p0 = eLDS[e],     p1 = eLDS[e + 1];
                const uint p2 = eLDS[e + 2], p3 = eLDS[e + 3];
                const uint u0 = z2[(size_t)(p0 & 0x1FFFFu) * 64 + lane];
                const uint u1 = z2[(size_t)(p1 & 0x1FFFFu) * 64 + lane];
                const uint u2 = z2[(size_t)(p2 & 0x1FFFFu) * 64 + lane];
                const uint u3 = z2[(size_t)(p3 & 0x1FFFFu) * 64 + lane];
                ax += blo(u0) + blo(u1) + blo(u2) + blo(u3);
                ay += bhi(u0) + bhi(u1) + bhi(u2) + bhi(u3);
            }
            for (; e < s1; ++e) {
                const uint u = z2[(size_t)(eLDS[e] & 0x1FFFFu) * 64 + lane];
                ax += blo(u); ay += bhi(u);
            }
            const float r = 1.0f / fmaxf((float)(s1 - s0), 1.0f);
            ((float2*)(out + (size_t)n * OUT_F))[lane] = make_float2(ax * r, ay * r);
        }
    } else {
        // statistically-unreachable overflow fallback: O(NPB * cnt), correct
        for (int j = wave; j < NPB; j += 8) {
            const int n = n0 + j;
            if (n >= N) continue;
            float ax = 0.f, ay = 0.f;
            int c = 0;
            for (int e = 0; e < cnt; ++e) {
                const uint p = csr[beg + e];
                if ((int)(p >> 17) == j) {
                    const uint u = z2[(size_t)(p & 0x1FFFFu) * 64 + lane];
                    ax += blo(u); ay += bhi(u); ++c;
                }
            }
            const float r = 1.0f / fmaxf((float)c, 1.0f);
            ((float2*)(out + (size_t)n * OUT_F))[lane] = make_float2(ax * r, ay * r);
        }
    }
}

extern "C" void kernel_launch(void* const* d_in, const int* in_sizes, int n_in,
                              void* d_out, int out_size, void* d_ws, size_t ws_size,
                              hipStream_t stream)
{
    const float* h   = (const float*)d_in[0];
    const float* W   = (const float*)d_in[1];
    const int*   src = (const int*)d_in[2];
    const int*   dst = (const int*)d_in[3];
    float*       out = (float*)d_out;

    const int N = in_sizes[0] / IN_F;   // 100000
    const int E = in_sizes[2];          // 1600000
    const int nb = (N + NPB - 1) / NPB; // 782 buckets

    ushort* zb   = (ushort*)d_ws;                      // [N, OUT_F] bf16, 25.6 MB
    int*    gcnt = (int*)(zb + (size_t)N * OUT_F);     // [nb]
    int*    off  = gcnt + MAXB;                        // [nb]
    int*    cur  = off + MAXB;                         // [nb]
    uint*   csr  = (uint*)(cur + MAXB);                // [E] packed

    hipMemsetAsync(gcnt, 0, (size_t)nb * sizeof(int), stream);

    gcn_gemm_mfma_kernel<<<(N + 255) / 256, 256, 0, stream>>>(h, W, zb, N);

    const int G = 256;
    const int chunk = (E + G - 1) / G;
    gcn_bhist_kernel<<<G, 256, 0, stream>>>(dst, gcnt, E, nb, chunk);
    gcn_bscan_kernel<<<1, 1024, 0, stream>>>(gcnt, off, cur, nb);
    gcn_part_kernel<<<G, 256, 0, stream>>>(src, dst, cur, csr, E, nb, chunk);

    gcn_sortgather_kernel<<<nb, 512, 0, stream>>>((const uint*)zb, csr, off, gcnt, out, N);
}